// Round 5
// baseline (192.065 us; speedup 1.0000x reference)
//
#include <hip/hip_runtime.h>

#define BB 4
#define CC 256
#define NN 8192
#define HH 4
#define NCH 16  // n-chunks for KV partial reduction

typedef unsigned short u16;
typedef __bf16 bf16x8 __attribute__((ext_vector_type(8)));
typedef float f32x4 __attribute__((ext_vector_type(4)));

__device__ __forceinline__ float bf2f(unsigned u) {
  return __uint_as_float(u << 16);
}
__device__ __forceinline__ u16 f2bf(float f) {
  unsigned u = __float_as_uint(f);
  return (u16)((u + 0x7fffu + ((u >> 16) & 1u)) >> 16);
}
__device__ __forceinline__ void bf8_to_f32(uint4 r, float* f) {
  f[0] = __uint_as_float(r.x << 16); f[1] = __uint_as_float(r.x & 0xffff0000u);
  f[2] = __uint_as_float(r.y << 16); f[3] = __uint_as_float(r.y & 0xffff0000u);
  f[4] = __uint_as_float(r.z << 16); f[5] = __uint_as_float(r.z & 0xffff0000u);
  f[6] = __uint_as_float(r.w << 16); f[7] = __uint_as_float(r.w & 0xffff0000u);
}
__device__ __forceinline__ void bf4_to_f32(uint2 r, float* f) {
  f[0] = __uint_as_float(r.x << 16); f[1] = __uint_as_float(r.x & 0xffff0000u);
  f[2] = __uint_as_float(r.y << 16); f[3] = __uint_as_float(r.y & 0xffff0000u);
}
// async global->LDS, 16B per lane. LDS dest is WAVE-UNIFORM base + lane*16 (linear!).
__device__ __forceinline__ void gload16(const u16* g, u16* l) {
  __builtin_amdgcn_global_load_lds(
      (const __attribute__((address_space(1))) unsigned int*)g,
      (__attribute__((address_space(3))) unsigned int*)l, 16, 0, 0);
}

// ---------------- fused weight f32 -> bf16 convert (all 6 weights) ----------------
__global__ __launch_bounds__(256) void cvt_all_kernel(
    const float* __restrict__ wq, const float* __restrict__ wk,
    const float* __restrict__ wv, const float* __restrict__ wa,
    const float* __restrict__ w1, const float* __restrict__ w2,
    u16* __restrict__ oq, u16* __restrict__ ok, u16* __restrict__ ov,
    u16* __restrict__ oa, u16* __restrict__ o1, u16* __restrict__ o2) {
  int i = blockIdx.x * 256 + threadIdx.x;  // [0, 655360)
  const float* src;
  u16* dst;
  int off;
  if (i < 65536) { src = wq; dst = oq; off = i; }
  else if (i < 131072) { src = wk; dst = ok; off = i - 65536; }
  else if (i < 196608) { src = wv; dst = ov; off = i - 131072; }
  else if (i < 262144) { src = wa; dst = oa; off = i - 196608; }
  else if (i < 524288) { src = w1; dst = o1; off = i - 262144; }
  else { src = w2; dst = o2; off = i - 524288; }
  dst[off] = f2bf(src[off]);
}

// ---------------- x [B,C,N] f32 -> xt [B,N,C] bf16 (z<4: x1, z>=4: x2) ----------------
__global__ __launch_bounds__(256) void transpose_kernel(const float* __restrict__ x1,
                                                        const float* __restrict__ x2,
                                                        u16* __restrict__ x1t,
                                                        u16* __restrict__ x2t) {
  __shared__ float T[64][65];
  const int bz = blockIdx.z;
  const int b = bz & 3;
  const float* x = (bz < 4) ? x1 : x2;
  u16* xt = (bz < 4) ? x1t : x2t;
  const int c0 = blockIdx.y * 64, n0 = blockIdx.x * 64;
  const float* xp = x + ((size_t)b * CC + c0) * NN + n0;
#pragma unroll
  for (int it = 0; it < 4; ++it) {
    int idx = threadIdx.x + it * 256;
    int r = idx >> 4, seg = idx & 15;
    float4 v = *(const float4*)(xp + (size_t)r * NN + seg * 4);
    T[r][seg * 4 + 0] = v.x; T[r][seg * 4 + 1] = v.y;
    T[r][seg * 4 + 2] = v.z; T[r][seg * 4 + 3] = v.w;
  }
  __syncthreads();
  u16* op = xt + ((size_t)b * NN + n0) * CC + c0;
  const int j = threadIdx.x >> 2, g = threadIdx.x & 3;
#pragma unroll
  for (int i = 0; i < 4; ++i) {
    int c = g * 16 + i * 4;
    uint2 pk;
    pk.x = (unsigned)f2bf(T[c + 0][j]) | ((unsigned)f2bf(T[c + 1][j]) << 16);
    pk.y = (unsigned)f2bf(T[c + 2][j]) | ((unsigned)f2bf(T[c + 3][j]) << 16);
    *(uint2*)(op + (size_t)j * CC + c) = pk;
  }
}

// ---------------- generic 128x128 MFMA GEMM: out[m,o] = epi(sum_k A[m,k]*W[o,k]) ----------------
// global_load_lds staging into LINEAR (unpadded) LDS tiles; m97-family 2-barrier loop.
// MODE 0: Q proj  (elu+1), out [B*N, C]
// MODE 1: K proj  (elu+1), out TRANSPOSED [B, C, N]
// MODE 2: V proj  (+bias), out TRANSPOSED [B, C, N]
// MODE 3: aug proj + BatchNorm fold
// MODE 4: MLP1 relu, A split: k<256 from A1, k>=256 from A2 (both stride 256)
// MODE 5: MLP2 plain
template <int MODE>
__global__ __launch_bounds__(256) void gemm_kernel(
    const u16* __restrict__ A1, const u16* __restrict__ A2,
    const u16* __restrict__ W, const float* __restrict__ bias,
    const float* __restrict__ e0, const float* __restrict__ e1,
    const float* __restrict__ e2, const float* __restrict__ e3,
    u16* __restrict__ outp, int K, int O) {
  __shared__ u16 As[128 * 64];
  __shared__ u16 Ws[128 * 64];
  const int m0 = blockIdx.x * 128, o0 = blockIdx.y * 128;
  const int tid = threadIdx.x, lane = tid & 63, wave = tid >> 6;
  const int wm = (wave >> 1) * 64, wo = (wave & 1) * 64;
  const int fr = lane & 15, fq = lane >> 4;
  f32x4 acc[4][4] = {};
  const int nkt = K >> 6;
  for (int kt = 0; kt < nkt; ++kt) {
    const int k0 = kt << 6;
    const u16* Ap;
    int rsA;
    if (MODE == 4) {
      Ap = (k0 < 256) ? (A1 + k0) : (A2 + (k0 - 256));
      rsA = 256;
    } else {
      Ap = A1 + k0;
      rsA = K;
    }
    const u16* Wp = W + k0;
#pragma unroll
    for (int i = 0; i < 4; ++i) {
      int idx = tid + i * 256;
      int rr = idx >> 3, ss = idx & 7;
      gload16(Ap + (size_t)(m0 + rr) * rsA + ss * 8, &As[(i * 256 + wave * 64) * 8]);
      gload16(Wp + (size_t)(o0 + rr) * K + ss * 8, &Ws[(i * 256 + wave * 64) * 8]);
    }
    __syncthreads();  // compiler drains vmcnt before s_barrier
#pragma unroll
    for (int kk = 0; kk < 2; ++kk) {
      bf16x8 af[4], bfr[4];
#pragma unroll
      for (int mi = 0; mi < 4; ++mi)
        af[mi] = __builtin_bit_cast(bf16x8, *(const uint4*)(&As[(wm + mi * 16 + fr) * 64 + kk * 32 + fq * 8]));
#pragma unroll
      for (int oi = 0; oi < 4; ++oi)
        bfr[oi] = __builtin_bit_cast(bf16x8, *(const uint4*)(&Ws[(wo + oi * 16 + fr) * 64 + kk * 32 + fq * 8]));
#pragma unroll
      for (int mi = 0; mi < 4; ++mi)
#pragma unroll
        for (int oi = 0; oi < 4; ++oi)
          acc[mi][oi] = __builtin_amdgcn_mfma_f32_16x16x32_bf16(af[mi], bfr[oi], acc[mi][oi], 0, 0, 0);
    }
    __syncthreads();
  }
  // epilogue
  const int bb_ = m0 >> 13;       // batch (tiles never straddle batch: 128 | 8192)
  const int nb = m0 & (NN - 1);   // n-offset within batch (for transposed modes)
#pragma unroll
  for (int oi = 0; oi < 4; ++oi) {
    const int col = o0 + wo + oi * 16 + fr;
    float b0 = 0.f, sc = 1.f, sh = 0.f;
    if (MODE == 0 || MODE == 1 || MODE == 2) b0 = bias[col];
    if (MODE == 3) {
      sc = e0[col] * rsqrtf(e3[col] + 1e-5f);
      sh = (bias[col] - e2[col]) * sc + e1[col];
    }
#pragma unroll
    for (int mi = 0; mi < 4; ++mi) {
      const int rowb = m0 + wm + mi * 16 + fq * 4;
      if (MODE == 1 || MODE == 2) {
        // transposed write: out[b, col, n], 4 consecutive n packed into one 8B store
        float v[4];
#pragma unroll
        for (int r = 0; r < 4; ++r) {
          float t = acc[mi][oi][r] + b0;
          if (MODE == 1) t = (t > 0.f) ? (t + 1.f) : __expf(t);
          v[r] = t;
        }
        uint2 pk;
        pk.x = (unsigned)f2bf(v[0]) | ((unsigned)f2bf(v[1]) << 16);
        pk.y = (unsigned)f2bf(v[2]) | ((unsigned)f2bf(v[3]) << 16);
        const int nloc = nb + wm + mi * 16 + fq * 4;
        *(uint2*)(outp + ((size_t)bb_ * CC + col) * NN + nloc) = pk;
      } else {
#pragma unroll
        for (int r = 0; r < 4; ++r) {
          float v = acc[mi][oi][r];
          if (MODE == 0) {
            v += b0;
            v = (v > 0.f) ? (v + 1.f) : __expf(v);
          } else if (MODE == 3) {
            v = v * sc + sh;
          } else if (MODE == 4) {
            v = fmaxf(v, 0.f);
          }
          outp[(size_t)(rowb + r) * O + col] = f2bf(v);
        }
      }
    }
  }
}

// ---------------- Ksum[b,c] = sum_n K2[b,c,n]  (coalesced, no atomics) ----------------
__global__ __launch_bounds__(256) void ksum_kernel(const u16* __restrict__ K2,
                                                   float* __restrict__ Ksum) {
  __shared__ float red[4];
  const int b = blockIdx.y, c = blockIdx.x, tid = threadIdx.x;
  const u16* p = K2 + ((size_t)b * CC + c) * NN;
  float acc = 0.f;
#pragma unroll
  for (int j = 0; j < 4; ++j) {
    uint4 raw = *(const uint4*)(p + (j * 256 + tid) * 8);
    float f[8];
    bf8_to_f32(raw, f);
#pragma unroll
    for (int q = 0; q < 8; ++q) acc += f[q];
  }
#pragma unroll
  for (int m = 1; m < 64; m <<= 1) acc += __shfl_xor(acc, m);
  if ((tid & 63) == 0) red[tid >> 6] = acc;
  __syncthreads();
  if (tid == 0) Ksum[b * CC + c] = red[0] + red[1] + red[2] + red[3];
}

// ---------------- KV partials via MFMA: Pkv[ch,bh,dk,dv] = sum_{n in chunk} K2[.,dk,n]*V2[.,dv,n] ----------------
__global__ __launch_bounds__(256) void kvpartial_kernel(const u16* __restrict__ K2,
                                                        const u16* __restrict__ V2,
                                                        float* __restrict__ Pkv) {
  __shared__ u16 Ks[64 * 64];
  __shared__ u16 Vs[64 * 64];
  const int b = blockIdx.z, h = blockIdx.y, ch = blockIdx.x;
  const int tid = threadIdx.x, lane = tid & 63, w = tid >> 6;
  const int fr = lane & 15, fq = lane >> 4;
  const size_t base = ((size_t)b * CC + h * 64) * NN + (size_t)ch * (NN / NCH);
  f32x4 acc[4] = {};
  for (int step = 0; step < (NN / NCH) / 64; ++step) {
#pragma unroll
    for (int i = 0; i < 2; ++i) {
      int idx = tid + i * 256;
      int rr = idx >> 3, ss = idx & 7;
      gload16(K2 + base + (size_t)rr * NN + step * 64 + ss * 8, &Ks[(i * 256 + w * 64) * 8]);
      gload16(V2 + base + (size_t)rr * NN + step * 64 + ss * 8, &Vs[(i * 256 + w * 64) * 8]);
    }
    __syncthreads();
#pragma unroll
    for (int kk = 0; kk < 2; ++kk) {
      bf16x8 af = __builtin_bit_cast(bf16x8, *(const uint4*)(&Ks[(w * 16 + fr) * 64 + kk * 32 + fq * 8]));
#pragma unroll
      for (int oi = 0; oi < 4; ++oi) {
        bf16x8 bfr = __builtin_bit_cast(bf16x8, *(const uint4*)(&Vs[(oi * 16 + fr) * 64 + kk * 32 + fq * 8]));
        acc[oi] = __builtin_amdgcn_mfma_f32_16x16x32_bf16(af, bfr, acc[oi], 0, 0, 0);
      }
    }
    __syncthreads();
  }
  // D[dk][dv]: dk = w*16 + fq*4 + r, dv = oi*16 + fr
  float* o = Pkv + (((size_t)ch * (BB * HH) + b * HH + h) << 12);
#pragma unroll
  for (int oi = 0; oi < 4; ++oi)
#pragma unroll
    for (int r = 0; r < 4; ++r)
      o[(w * 16 + fq * 4 + r) * 64 + oi * 16 + fr] = acc[oi][r];
}

// ---------------- KVT[bh][dv][dk] = bf16( sum_ch Pkv[ch][bh][dk][dv] ) ----------------
__global__ __launch_bounds__(256) void kvreduce_kernel(const float* __restrict__ Pkv,
                                                       u16* __restrict__ KVT) {
  int i = blockIdx.x * 256 + threadIdx.x;  // [0, 65536) = [bh][dk][dv] for coalesced reads
  int bh = i >> 12, dk = (i >> 6) & 63, dv = i & 63;
  float s = 0.f;
#pragma unroll
  for (int ch = 0; ch < NCH; ++ch)
    s += Pkv[(((size_t)ch * (BB * HH) + bh) << 12) + (dk << 6) + dv];
  KVT[((size_t)bh << 12) + (dv << 6) + dk] = f2bf(s);
}

// ---------------- msg GEMM with fused score/Z ----------------
// msg[m, h*64+v] = Z[m,h] * sum_d Qt[m,h*64+d]*KVT[b,h,v,d]
// Z[m,h] = 1/(where(dot(Q[m,h,:],Ksum[b,h,:]) > thr)+eps)  -- uses the same LDS A-tile
__global__ __launch_bounds__(256) void msggemm_kernel(const u16* __restrict__ Qt,
                                                      const u16* __restrict__ KVT,
                                                      const float* __restrict__ Ksum,
                                                      const float* __restrict__ thrp,
                                                      u16* __restrict__ msgout) {
  __shared__ u16 As[128 * 64];
  __shared__ u16 Ws[64 * 64];
  __shared__ float Zs[128];
  const int m0 = blockIdx.x * 128, h = blockIdx.y, b = blockIdx.z;
  const int tid = threadIdx.x, lane = tid & 63, wave = tid >> 6;
  const int wm = (wave >> 1) * 64, wo = (wave & 1) * 32;
  const int fr = lane & 15, fq = lane >> 4;
  const float thrv = thrp[0];
  const u16* Ap = Qt + ((size_t)b * NN + m0) * CC + h * 64;
#pragma unroll
  for (int i = 0; i < 4; ++i) {
    int idx = tid + i * 256;
    int rr = idx >> 3, ss = idx & 7;
    gload16(Ap + (size_t)rr * CC + ss * 8, &As[(i * 256 + wave * 64) * 8]);
  }
  const u16* Wp = KVT + (((size_t)b * HH + h) << 12);
#pragma unroll
  for (int i = 0; i < 2; ++i) {
    int idx = tid + i * 256;
    int rr = idx >> 3, ss = idx & 7;
    gload16(Wp + (size_t)rr * 64 + ss * 8, &Ws[(i * 256 + wave * 64) * 8]);
  }
  __syncthreads();
  // fused score: 2 threads per row, 32 elems each
  {
    const int row = tid >> 1, half = tid & 1;
    const float* ksh = Ksum + b * CC + h * 64 + half * 32;
    float za = 0.f;
#pragma unroll
    for (int j8 = 0; j8 < 4; ++j8) {
      uint4 raw = *(const uint4*)(&As[row * 64 + half * 32 + j8 * 8]);
      float f[8];
      bf8_to_f32(raw, f);
#pragma unroll
      for (int j = 0; j < 8; ++j) za += f[j] * ksh[j8 * 8 + j];
    }
    za += __shfl_xor(za, 1);
    if (half == 0) Zs[row] = 1.f / (((za > thrv) ? za : 0.f) + 1e-6f);
  }
  f32x4 acc[4][2] = {};
#pragma unroll
  for (int kk = 0; kk < 2; ++kk) {
    bf16x8 af[4], bfr[2];
#pragma unroll
    for (int mi = 0; mi < 4; ++mi)
      af[mi] = __builtin_bit_cast(bf16x8, *(const uint4*)(&As[(wm + mi * 16 + fr) * 64 + kk * 32 + fq * 8]));
#pragma unroll
    for (int oi = 0; oi < 2; ++oi)
      bfr[oi] = __builtin_bit_cast(bf16x8, *(const uint4*)(&Ws[(wo + oi * 16 + fr) * 64 + kk * 32 + fq * 8]));
#pragma unroll
    for (int mi = 0; mi < 4; ++mi)
#pragma unroll
      for (int oi = 0; oi < 2; ++oi)
        acc[mi][oi] = __builtin_amdgcn_mfma_f32_16x16x32_bf16(af[mi], bfr[oi], acc[mi][oi], 0, 0, 0);
  }
  __syncthreads();  // Zs visible to all
#pragma unroll
  for (int oi = 0; oi < 2; ++oi) {
    const int col = h * 64 + wo + oi * 16 + fr;
#pragma unroll
    for (int mi = 0; mi < 4; ++mi) {
      const int rowb = wm + mi * 16 + fq * 4;
#pragma unroll
      for (int r = 0; r < 4; ++r) {
        const int row = rowb + r;
        msgout[((size_t)b * NN + m0 + row) * CC + col] = f2bf(acc[mi][oi][r] * Zs[row]);
      }
    }
  }
}

// ---------------- LayerNorm over C (one wave per row, 8B/lane); AUG adds aug row ----------------
// NOTE: must be called OUT-OF-PLACE (in != outb); in-place violates __restrict__.
template <bool AUG>
__global__ __launch_bounds__(256) void ln_kernel(const u16* __restrict__ in,
                                                 u16* __restrict__ outb,
                                                 const float* __restrict__ g,
                                                 const float* __restrict__ bb,
                                                 const u16* __restrict__ aug) {
  const int tid = threadIdx.x, lane = tid & 63, w = tid >> 6;
  const size_t row0 = (size_t)blockIdx.x * 32;
  float gv[4], bv[4];
#pragma unroll
  for (int q = 0; q < 4; ++q) {
    gv[q] = g[lane * 4 + q];
    bv[q] = bb[lane * 4 + q];
  }
  for (int i = 0; i < 8; ++i) {
    const size_t row = row0 + i * 4 + w;
    uint2 raw = *(const uint2*)(in + row * CC + lane * 4);
    float v[4];
    bf4_to_f32(raw, v);
    float s1 = v[0] + v[1] + v[2] + v[3];
    float s2 = v[0] * v[0] + v[1] * v[1] + v[2] * v[2] + v[3] * v[3];
#pragma unroll
    for (int m = 1; m < 64; m <<= 1) {
      s1 += __shfl_xor(s1, m);
      s2 += __shfl_xor(s2, m);
    }
    const float mean = s1 * (1.f / CC);
    const float var = s2 * (1.f / CC) - mean * mean;
    const float rs = rsqrtf(var + 1e-5f);
    float ov[4];
#pragma unroll
    for (int q = 0; q < 4; ++q) ov[q] = (v[q] - mean) * rs * gv[q] + bv[q];
    if (AUG) {
      uint2 ar = *(const uint2*)(aug + row * CC + lane * 4);
      float af[4];
      bf4_to_f32(ar, af);
#pragma unroll
      for (int q = 0; q < 4; ++q) ov[q] += af[q];
    }
    uint2 pk;
    pk.x = (unsigned)f2bf(ov[0]) | ((unsigned)f2bf(ov[1]) << 16);
    pk.y = (unsigned)f2bf(ov[2]) | ((unsigned)f2bf(ov[3]) << 16);
    *(uint2*)(outb + row * CC + lane * 4) = pk;
  }
}

// ---------------- out[b,c,n] = tv[b,n,c] + x1[b,c,n]  (f32 out) ----------------
__global__ __launch_bounds__(256) void addout_kernel(const u16* __restrict__ tv,
                                                     const float* __restrict__ x1,
                                                     float* __restrict__ outp) {
  __shared__ float T[64][65];
  const int b = blockIdx.z, c0 = blockIdx.y * 64, n0 = blockIdx.x * 64;
  const u16* tp = tv + ((size_t)b * NN + n0) * CC + c0;
#pragma unroll
  for (int i = 0; i < 2; ++i) {
    int idx = threadIdx.x + i * 256;
    int r = idx >> 3, s = idx & 7;  // r = n-local, s = c-seg (8 bf16)
    uint4 raw = *(const uint4*)(tp + (size_t)r * CC + s * 8);
    float f[8];
    bf8_to_f32(raw, f);
#pragma unroll
    for (int j = 0; j < 8; ++j) T[s * 8 + j][r] = f[j];
  }
  __syncthreads();
  const float* xp = x1 + ((size_t)b * CC + c0) * NN + n0;
  float* op = outp + ((size_t)b * CC + c0) * NN + n0;
#pragma unroll
  for (int i = 0; i < 16; ++i) {
    int idx = threadIdx.x + i * 256;
    int c = idx >> 6, j = idx & 63;
    op[(size_t)c * NN + j] = T[c][j] + xp[(size_t)c * NN + j];
  }
}

extern "C" void kernel_launch(void* const* d_in, const int* in_sizes, int n_in,
                              void* d_out, int out_size, void* d_ws, size_t ws_size,
                              hipStream_t stream) {
  (void)in_sizes; (void)n_in; (void)out_size; (void)ws_size;
  const float* x1 = (const float*)d_in[0];
  const float* x2 = (const float*)d_in[1];
  const float* Wq = (const float*)d_in[2];
  const float* bq = (const float*)d_in[3];
  const float* Wk = (const float*)d_in[4];
  const float* bk = (const float*)d_in[5];
  const float* Wv = (const float*)d_in[6];
  const float* bv = (const float*)d_in[7];
  const float* thr = (const float*)d_in[8];
  const float* W1 = (const float*)d_in[9];
  const float* W2 = (const float*)d_in[10];
  const float* g1 = (const float*)d_in[11];
  const float* b1 = (const float*)d_in[12];
  const float* g2 = (const float*)d_in[13];
  const float* b2 = (const float*)d_in[14];
  const float* Wa = (const float*)d_in[15];
  const float* ba = (const float*)d_in[16];
  const float* bng = (const float*)d_in[17];
  const float* bnb = (const float*)d_in[18];
  const float* bnm = (const float*)d_in[19];
  const float* bnv = (const float*)d_in[20];
  float* out = (float*)d_out;

  // Slot lifetime map (each slot SZ = 16.78 MB; all uses strictly stream-ordered):
  //  slot 0: x1t                    (live entire call)
  //  slot 1: x2t -> mlp2
  //  slot 2: Qt  -> h1(lo half)
  //  slot 3: K2  -> h1(hi half)
  //  slot 4: V2  -> msgN -> tv      (V2 dead after kvpartial; msgN: ln1 w -> gemm4 r; tv: ln2 w -> addout r)
  //  slot 5: augt                   (live until ln2)
  //  slot 6: Pkv (first 4MB) -> msgout (msggemm w -> ln1 r)
  char* ws = (char*)d_ws;
  constexpr size_t SZ = (size_t)BB * NN * CC * sizeof(u16);  // 16.78 MB
  u16* x1t = (u16*)(ws);
  u16* x2t = (u16*)(ws + SZ);
  u16* Qt = (u16*)(ws + 2 * SZ);
  u16* K2 = (u16*)(ws + 3 * SZ);  // [B,C,N] layout
  u16* V2 = (u16*)(ws + 4 * SZ);  // [B,C,N] layout
  u16* augt = (u16*)(ws + 5 * SZ);
  u16* msgout = (u16*)(ws + 6 * SZ);
  u16* h1 = Qt;      // slots 2+3 (33.55 MB contiguous)
  u16* mlp2 = x2t;   // slot 1, after x2t dead
  u16* msgN = V2;    // slot 4, after V2 dead (LN1 output -- OUT-OF-PLACE)
  u16* tv = V2;      // slot 4, after msgN consumed by gemm<4>
  float* Pkv = (float*)msgout;  // 4 MB partials; consumed by kvreduce before msggemm writes
  char* tail = ws + 7 * SZ;
  float* Ksum = (float*)tail;               // 4 KB
  u16* KVT = (u16*)(tail + 4096);           // 128 KB
  u16* Wqb = (u16*)(tail + 4096 + 131072);
  u16* Wkb = Wqb + CC * CC;
  u16* Wvb = Wkb + CC * CC;
  u16* Wab = Wvb + CC * CC;
  u16* W1b = Wab + CC * CC;
  u16* W2b = W1b + 512 * 512;
  // total ws use ~119 MiB

  // fused weight converts (one launch)
  cvt_all_kernel<<<dim3(2560), 256, 0, stream>>>(Wq, Wk, Wv, Wa, W1, W2,
                                                 Wqb, Wkb, Wvb, Wab, W1b, W2b);

  // fused transposes (x1 and x2 in one launch)
  transpose_kernel<<<dim3(NN / 64, CC / 64, 2 * BB), 256, 0, stream>>>(x1, x2, x1t, x2t);

  // projections (M = 32768 rows flattened across batch)
  gemm_kernel<0><<<dim3(256, 2), 256, 0, stream>>>(x1t, nullptr, Wqb, bq, nullptr, nullptr, nullptr, nullptr, Qt, 256, 256);
  gemm_kernel<1><<<dim3(256, 2), 256, 0, stream>>>(x2t, nullptr, Wkb, bk, nullptr, nullptr, nullptr, nullptr, K2, 256, 256);
  gemm_kernel<2><<<dim3(256, 2), 256, 0, stream>>>(x2t, nullptr, Wvb, bv, nullptr, nullptr, nullptr, nullptr, V2, 256, 256);
  gemm_kernel<3><<<dim3(256, 2), 256, 0, stream>>>(x1t, nullptr, Wab, ba, bng, bnb, bnm, bnv, augt, 256, 256);

  // attention core (no atomics anywhere)
  ksum_kernel<<<dim3(CC, BB), 256, 0, stream>>>(K2, Ksum);
  kvpartial_kernel<<<dim3(NCH, HH, BB), 256, 0, stream>>>(K2, V2, Pkv);
  kvreduce_kernel<<<dim3(256), 256, 0, stream>>>(Pkv, KVT);
  // msggemm fuses the score/Z computation (uses its LDS Q-tile); m0 is PER-BATCH
  msggemm_kernel<<<dim3(NN / 128, HH, BB), 256, 0, stream>>>(Qt, KVT, Ksum, thr, msgout);
  // LN1: OUT-OF-PLACE (msgout -> msgN)
  ln_kernel<false><<<dim3(1024), 256, 0, stream>>>(msgout, msgN, g1, b1, nullptr);

  // MLP
  gemm_kernel<4><<<dim3(256, 4), 256, 0, stream>>>(x1t, msgN, W1b, nullptr, nullptr, nullptr, nullptr, nullptr, h1, 512, 512);
  gemm_kernel<5><<<dim3(256, 2), 256, 0, stream>>>(h1, nullptr, W2b, nullptr, nullptr, nullptr, nullptr, nullptr, mlp2, 512, 256);

  // LN2 + aug, then transpose-add to output
  ln_kernel<true><<<dim3(1024), 256, 0, stream>>>(mlp2, tv, g2, b2, augt);
  addout_kernel<<<dim3(NN / 64, CC / 64, BB), 256, 0, stream>>>(tv, x1, out);
}

// Round 6
// 184.898 us; speedup vs baseline: 1.0388x; 1.0388x over previous
//
#include <hip/hip_runtime.h>

#define BB 4
#define CC 256
#define NN 8192
#define HH 4
#define NCH 16  // n-chunks for KV partial reduction

typedef unsigned short u16;
typedef __bf16 bf16x8 __attribute__((ext_vector_type(8)));
typedef float f32x4 __attribute__((ext_vector_type(4)));

__device__ __forceinline__ float bf2f(unsigned u) {
  return __uint_as_float(u << 16);
}
__device__ __forceinline__ u16 f2bf(float f) {
  unsigned u = __float_as_uint(f);
  return (u16)((u + 0x7fffu + ((u >> 16) & 1u)) >> 16);
}
__device__ __forceinline__ void bf8_to_f32(uint4 r, float* f) {
  f[0] = __uint_as_float(r.x << 16); f[1] = __uint_as_float(r.x & 0xffff0000u);
  f[2] = __uint_as_float(r.y << 16); f[3] = __uint_as_float(r.y & 0xffff0000u);
  f[4] = __uint_as_float(r.z << 16); f[5] = __uint_as_float(r.z & 0xffff0000u);
  f[6] = __uint_as_float(r.w << 16); f[7] = __uint_as_float(r.w & 0xffff0000u);
}
// async global->LDS, 16B/lane; LDS dest = wave-uniform base + lane*16 (linear only)
__device__ __forceinline__ void gload16(const u16* g, u16* l) {
  __builtin_amdgcn_global_load_lds(
      (const __attribute__((address_space(1))) unsigned int*)g,
      (__attribute__((address_space(3))) unsigned int*)l, 16, 0, 0);
}

// ---------------- fused weight f32 -> bf16 convert (all 6 weights) ----------------
__global__ __launch_bounds__(256) void cvt_all_kernel(
    const float* __restrict__ wq, const float* __restrict__ wk,
    const float* __restrict__ wv, const float* __restrict__ wa,
    const float* __restrict__ w1, const float* __restrict__ w2,
    u16* __restrict__ oq, u16* __restrict__ ok, u16* __restrict__ ov,
    u16* __restrict__ oa, u16* __restrict__ o1, u16* __restrict__ o2) {
  int i = blockIdx.x * 256 + threadIdx.x;  // [0, 655360)
  const float* src;
  u16* dst;
  int off;
  if (i < 65536) { src = wq; dst = oq; off = i; }
  else if (i < 131072) { src = wk; dst = ok; off = i - 65536; }
  else if (i < 196608) { src = wv; dst = ov; off = i - 131072; }
  else if (i < 262144) { src = wa; dst = oa; off = i - 196608; }
  else if (i < 524288) { src = w1; dst = o1; off = i - 262144; }
  else { src = w2; dst = o2; off = i - 524288; }
  dst[off] = f2bf(src[off]);
}

// ---------------- x [B,C,N] f32 -> xt [B,N,C] bf16 (z<4: x1, z>=4: x2) ----------------
__global__ __launch_bounds__(256) void transpose_kernel(const float* __restrict__ x1,
                                                        const float* __restrict__ x2,
                                                        u16* __restrict__ x1t,
                                                        u16* __restrict__ x2t) {
  __shared__ float T[64][65];
  const int bz = blockIdx.z;
  const int b = bz & 3;
  const float* x = (bz < 4) ? x1 : x2;
  u16* xt = (bz < 4) ? x1t : x2t;
  const int c0 = blockIdx.y * 64, n0 = blockIdx.x * 64;
  const float* xp = x + ((size_t)b * CC + c0) * NN + n0;
#pragma unroll
  for (int it = 0; it < 4; ++it) {
    int idx = threadIdx.x + it * 256;
    int r = idx >> 4, seg = idx & 15;
    float4 v = *(const float4*)(xp + (size_t)r * NN + seg * 4);
    T[r][seg * 4 + 0] = v.x; T[r][seg * 4 + 1] = v.y;
    T[r][seg * 4 + 2] = v.z; T[r][seg * 4 + 3] = v.w;
  }
  __syncthreads();
  u16* op = xt + ((size_t)b * NN + n0) * CC + c0;
  const int j = threadIdx.x >> 2, g = threadIdx.x & 3;
#pragma unroll
  for (int i = 0; i < 4; ++i) {
    int c = g * 16 + i * 4;
    uint2 pk;
    pk.x = (unsigned)f2bf(T[c + 0][j]) | ((unsigned)f2bf(T[c + 1][j]) << 16);
    pk.y = (unsigned)f2bf(T[c + 2][j]) | ((unsigned)f2bf(T[c + 3][j]) << 16);
    *(uint2*)(op + (size_t)j * CC + c) = pk;
  }
}

// ---------------- all 4 projections in one launch; mode = blockIdx.z ----------------
// mode 0: Q = elu(x1t.Wq+bq)+1      -> Qt   [B*N, C]
// mode 1: K = elu(x2t.Wk+bk)+1      -> K2   [B, C, N]  (transposed)
// mode 2: V = x2t.Wv+bv             -> V2   [B, C, N]  (transposed)
// mode 3: aug = BN(x1t.Wa+ba)       -> augt [B*N, C]
__global__ __launch_bounds__(256) void proj_all_kernel(
    const u16* __restrict__ x1t, const u16* __restrict__ x2t,
    const u16* __restrict__ Wqb, const u16* __restrict__ Wkb,
    const u16* __restrict__ Wvb, const u16* __restrict__ Wab,
    const float* __restrict__ bq, const float* __restrict__ bk,
    const float* __restrict__ bv, const float* __restrict__ ba,
    const float* __restrict__ bng, const float* __restrict__ bnb,
    const float* __restrict__ bnm, const float* __restrict__ bnv,
    u16* __restrict__ Qt, u16* __restrict__ K2, u16* __restrict__ V2,
    u16* __restrict__ augt) {
  __shared__ u16 As[128][72];
  __shared__ u16 Ws[128][72];
  const int mode = blockIdx.z;
  const u16* A = (mode == 0 || mode == 3) ? x1t : x2t;
  const u16* W = (mode == 0) ? Wqb : (mode == 1) ? Wkb : (mode == 2) ? Wvb : Wab;
  const float* bias = (mode == 0) ? bq : (mode == 1) ? bk : (mode == 2) ? bv : ba;
  u16* outp = (mode == 0) ? Qt : (mode == 1) ? K2 : (mode == 2) ? V2 : augt;
  const int m0 = blockIdx.x * 128, o0 = blockIdx.y * 128;
  const int tid = threadIdx.x, lane = tid & 63, wave = tid >> 6;
  const int wm = (wave >> 1) * 64, wo = (wave & 1) * 64;
  const int fr = lane & 15, fq = lane >> 4;
  f32x4 acc[4][4] = {};
  for (int kt = 0; kt < 4; ++kt) {
    const int k0 = kt << 6;
#pragma unroll
    for (int i = 0; i < 4; ++i) {
      int idx = tid + i * 256;
      int r = idx >> 3, s = idx & 7;
      *(uint4*)(&As[r][s * 8]) = *(const uint4*)(A + (size_t)(m0 + r) * CC + k0 + s * 8);
      *(uint4*)(&Ws[r][s * 8]) = *(const uint4*)(W + (size_t)(o0 + r) * CC + k0 + s * 8);
    }
    __syncthreads();
#pragma unroll
    for (int kk = 0; kk < 2; ++kk) {
      bf16x8 af[4], bfr[4];
#pragma unroll
      for (int mi = 0; mi < 4; ++mi)
        af[mi] = __builtin_bit_cast(bf16x8, *(const uint4*)(&As[wm + mi * 16 + fr][kk * 32 + fq * 8]));
#pragma unroll
      for (int oi = 0; oi < 4; ++oi)
        bfr[oi] = __builtin_bit_cast(bf16x8, *(const uint4*)(&Ws[wo + oi * 16 + fr][kk * 32 + fq * 8]));
#pragma unroll
      for (int mi = 0; mi < 4; ++mi)
#pragma unroll
        for (int oi = 0; oi < 4; ++oi)
          acc[mi][oi] = __builtin_amdgcn_mfma_f32_16x16x32_bf16(af[mi], bfr[oi], acc[mi][oi], 0, 0, 0);
    }
    __syncthreads();
  }
  const int bb_ = m0 >> 13;      // batch (tiles never straddle: 128 | 8192)
  const int nb = m0 & (NN - 1);  // n-offset within batch
#pragma unroll
  for (int oi = 0; oi < 4; ++oi) {
    const int col = o0 + wo + oi * 16 + fr;
    float b0 = bias[col], sc = 1.f, sh = 0.f;
    if (mode == 3) {
      sc = bng[col] * rsqrtf(bnv[col] + 1e-5f);
      sh = (b0 - bnm[col]) * sc + bnb[col];
    }
#pragma unroll
    for (int mi = 0; mi < 4; ++mi) {
      if (mode == 1 || mode == 2) {
        float v[4];
#pragma unroll
        for (int r = 0; r < 4; ++r) {
          float t = acc[mi][oi][r] + b0;
          if (mode == 1) t = (t > 0.f) ? (t + 1.f) : __expf(t);
          v[r] = t;
        }
        uint2 pk;
        pk.x = (unsigned)f2bf(v[0]) | ((unsigned)f2bf(v[1]) << 16);
        pk.y = (unsigned)f2bf(v[2]) | ((unsigned)f2bf(v[3]) << 16);
        const int nloc = nb + wm + mi * 16 + fq * 4;
        *(uint2*)(outp + ((size_t)bb_ * CC + col) * NN + nloc) = pk;
      } else {
        const int rowb = m0 + wm + mi * 16 + fq * 4;
#pragma unroll
        for (int r = 0; r < 4; ++r) {
          float v = acc[mi][oi][r];
          if (mode == 0) {
            v += b0;
            v = (v > 0.f) ? (v + 1.f) : __expf(v);
          } else {  // mode 3
            v = v * sc + sh;
          }
          outp[(size_t)(rowb + r) * CC + col] = f2bf(v);
        }
      }
    }
  }
}

// ---------------- KV partials via MFMA + fused per-chunk Ksum partials ----------------
// Pkv[ch,bh,dk,dv] = sum_{n in chunk} K2[b,h*64+dk,n]*V2[b,h*64+dv,n]
// Pks[(ch*BB+b)*CC + h*64+dk] = sum_{n in chunk} K2[b,h*64+dk,n]
__global__ __launch_bounds__(256) void kvpartial_kernel(const u16* __restrict__ K2,
                                                        const u16* __restrict__ V2,
                                                        float* __restrict__ Pkv,
                                                        float* __restrict__ Pks) {
  __shared__ u16 Ks[64 * 64];
  __shared__ u16 Vs[64 * 64];
  const int b = blockIdx.z, h = blockIdx.y, ch = blockIdx.x;
  const int tid = threadIdx.x, lane = tid & 63, w = tid >> 6;
  const int fr = lane & 15, fq = lane >> 4;
  const size_t base = ((size_t)b * CC + h * 64) * NN + (size_t)ch * (NN / NCH);
  f32x4 acc[4] = {};
  const int krow = tid >> 2, kq = tid & 3;  // for Ksum partial: 4 threads/dk-row
  float ksacc = 0.f;
  for (int step = 0; step < (NN / NCH) / 64; ++step) {
#pragma unroll
    for (int i = 0; i < 2; ++i) {
      int idx = tid + i * 256;
      int rr = idx >> 3, ss = idx & 7;
      gload16(K2 + base + (size_t)rr * NN + step * 64 + ss * 8, &Ks[(i * 256 + w * 64) * 8]);
      gload16(V2 + base + (size_t)rr * NN + step * 64 + ss * 8, &Vs[(i * 256 + w * 64) * 8]);
    }
    __syncthreads();
    // Ksum partial from the staged LDS tile (Ks is row-major [dk][n])
#pragma unroll
    for (int j = 0; j < 16; ++j) ksacc += bf2f(Ks[krow * 64 + kq * 16 + j]);
#pragma unroll
    for (int kk = 0; kk < 2; ++kk) {
      bf16x8 af = __builtin_bit_cast(bf16x8, *(const uint4*)(&Ks[(w * 16 + fr) * 64 + kk * 32 + fq * 8]));
#pragma unroll
      for (int oi = 0; oi < 4; ++oi) {
        bf16x8 bfr = __builtin_bit_cast(bf16x8, *(const uint4*)(&Vs[(oi * 16 + fr) * 64 + kk * 32 + fq * 8]));
        acc[oi] = __builtin_amdgcn_mfma_f32_16x16x32_bf16(af, bfr, acc[oi], 0, 0, 0);
      }
    }
    __syncthreads();
  }
  ksacc += __shfl_xor(ksacc, 1);
  ksacc += __shfl_xor(ksacc, 2);
  if (kq == 0) Pks[((size_t)ch * BB + b) * CC + h * 64 + krow] = ksacc;
  // D[dk][dv]: dk = w*16 + fq*4 + r, dv = oi*16 + fr
  float* o = Pkv + (((size_t)ch * (BB * HH) + b * HH + h) << 12);
#pragma unroll
  for (int oi = 0; oi < 4; ++oi)
#pragma unroll
    for (int r = 0; r < 4; ++r)
      o[(w * 16 + fq * 4 + r) * 64 + oi * 16 + fr] = acc[oi][r];
}

// ---------------- KVT[bh][dv][dk] = bf16( sum_ch Pkv ) ; Ksum[i<1024] = sum_ch Pks ----------------
__global__ __launch_bounds__(256) void kvreduce_kernel(const float* __restrict__ Pkv,
                                                       const float* __restrict__ Pks,
                                                       u16* __restrict__ KVT,
                                                       float* __restrict__ Ksum) {
  int i = blockIdx.x * 256 + threadIdx.x;  // [0, 65536)
  int bh = i >> 12, dk = (i >> 6) & 63, dv = i & 63;
  float s = 0.f;
#pragma unroll
  for (int ch = 0; ch < NCH; ++ch)
    s += Pkv[(((size_t)ch * (BB * HH) + bh) << 12) + (dk << 6) + dv];
  KVT[((size_t)bh << 12) + (dv << 6) + dk] = f2bf(s);
  if (i < BB * CC) {
    float t = 0.f;
#pragma unroll
    for (int ch = 0; ch < NCH; ++ch) t += Pks[ch * (BB * CC) + i];
    Ksum[i] = t;
  }
}

// ---------------- bigmsg: all-heads msg GEMM + fused score/Z + fused LN1 ----------------
// per block: 64 rows (per-batch), all 256 cols. wave w = head w.
// msgN[b,n,:] = LN( Z[n,h]*sum_d Q[n,h*64+d]*KVT[b,h,v,d] ) * g1 + b1
__global__ __launch_bounds__(256) void bigmsg_kernel(const u16* __restrict__ Qt,
                                                     const u16* __restrict__ KVT,
                                                     const float* __restrict__ Ksum,
                                                     const float* __restrict__ thrp,
                                                     const float* __restrict__ g1,
                                                     const float* __restrict__ b1,
                                                     u16* __restrict__ msgN) {
  // phase A: As[64][264] (Q) | Ws[4][64][72] (KVT).  phase B: Ml[64][272] (msg, overlaps As)
  __shared__ u16 lds[64 * 264 + 4 * 64 * 72];  // 35328 u16 = 70.7 KB
  __shared__ float Zs[64 * 4];
  u16* As = lds;
  u16* Ws = lds + 64 * 264;
  u16* Ml = lds;
  const int m0 = blockIdx.x * 64;  // per-batch row
  const int b = blockIdx.z;
  const int tid = threadIdx.x, lane = tid & 63, w = tid >> 6;
  const int fr = lane & 15, fq = lane >> 4;
  // stage Q tile 64x256
  const u16* Ap = Qt + ((size_t)b * NN + m0) * CC;
#pragma unroll
  for (int i = 0; i < 8; ++i) {
    int idx = tid + i * 256;            // 0..2047
    int rr = idx >> 5, ss = idx & 31;   // 64 rows x 32 seg8
    *(uint4*)(&As[rr * 264 + ss * 8]) = *(const uint4*)(Ap + (size_t)rr * CC + ss * 8);
  }
  // stage KVT all 4 heads (each [64][64])
  const u16* Wp = KVT + ((size_t)(b * HH) << 12);
#pragma unroll
  for (int i = 0; i < 8; ++i) {
    int idx = tid + i * 256;
    int h = idx >> 9, rr = (idx >> 3) & 63, ss = idx & 7;
    *(uint4*)(&Ws[(h * 64 + rr) * 72 + ss * 8]) = *(const uint4*)(Wp + ((size_t)h << 12) + rr * 64 + ss * 8);
  }
  __syncthreads();
  // fused score: thread (row, h) does the full 64-dim dot
  {
    const int row = tid >> 2, h = tid & 3;
    const float* ks = Ksum + b * CC + h * 64;
    float za = 0.f;
#pragma unroll
    for (int j8 = 0; j8 < 8; ++j8) {
      uint4 raw = *(const uint4*)(&As[row * 264 + h * 64 + j8 * 8]);
      float f[8];
      bf8_to_f32(raw, f);
#pragma unroll
      for (int j = 0; j < 8; ++j) za += f[j] * ks[j8 * 8 + j];
    }
    const float thrv = thrp[0];
    Zs[row * 4 + h] = 1.f / (((za > thrv) ? za : 0.f) + 1e-6f);
  }
  // msg MFMA: wave w handles head w (64 rows x 64 cols, K=64)
  f32x4 acc[4][4] = {};
#pragma unroll
  for (int kk = 0; kk < 2; ++kk) {
    bf16x8 af[4], bfr[4];
#pragma unroll
    for (int mi = 0; mi < 4; ++mi)
      af[mi] = __builtin_bit_cast(bf16x8, *(const uint4*)(&As[(mi * 16 + fr) * 264 + w * 64 + kk * 32 + fq * 8]));
#pragma unroll
    for (int oi = 0; oi < 4; ++oi)
      bfr[oi] = __builtin_bit_cast(bf16x8, *(const uint4*)(&Ws[(w * 64 + oi * 16 + fr) * 72 + kk * 32 + fq * 8]));
#pragma unroll
    for (int mi = 0; mi < 4; ++mi)
#pragma unroll
      for (int oi = 0; oi < 4; ++oi)
        acc[mi][oi] = __builtin_amdgcn_mfma_f32_16x16x32_bf16(af[mi], bfr[oi], acc[mi][oi], 0, 0, 0);
  }
  __syncthreads();  // all As/Ws reads done; Zs visible
  // write msg*Z into Ml (overlaps As region)
#pragma unroll
  for (int oi = 0; oi < 4; ++oi) {
    const int col = w * 64 + oi * 16 + fr;
#pragma unroll
    for (int mi = 0; mi < 4; ++mi) {
#pragma unroll
      for (int r = 0; r < 4; ++r) {
        const int row = mi * 16 + fq * 4 + r;
        Ml[row * 272 + col] = f2bf(acc[mi][oi][r] * Zs[row * 4 + w]);
      }
    }
  }
  __syncthreads();
  // fused LN1: 4 threads per row, 64 cols each; two-pass over LDS
  {
    const int row = tid >> 2, q = tid & 3;
    const u16* mrow = &Ml[row * 272 + q * 64];
    float s1 = 0.f, s2 = 0.f;
#pragma unroll
    for (int j8 = 0; j8 < 8; ++j8) {
      uint4 raw = *(const uint4*)(mrow + j8 * 8);
      float f[8];
      bf8_to_f32(raw, f);
#pragma unroll
      for (int j = 0; j < 8; ++j) {
        s1 += f[j];
        s2 += f[j] * f[j];
      }
    }
    s1 += __shfl_xor(s1, 1); s2 += __shfl_xor(s2, 1);
    s1 += __shfl_xor(s1, 2); s2 += __shfl_xor(s2, 2);
    const float mean = s1 * (1.f / CC);
    const float var = s2 * (1.f / CC) - mean * mean;
    const float rs = rsqrtf(var + 1e-5f);
    u16* orow = msgN + ((size_t)b * NN + m0 + row) * CC + q * 64;
#pragma unroll
    for (int j8 = 0; j8 < 8; ++j8) {
      uint4 raw = *(const uint4*)(mrow + j8 * 8);
      float f[8];
      bf8_to_f32(raw, f);
      const int cb = q * 64 + j8 * 8;
      unsigned pk[4];
#pragma unroll
      for (int e = 0; e < 4; ++e) {
        float lo = (f[2 * e] - mean) * rs * g1[cb + 2 * e] + b1[cb + 2 * e];
        float hi = (f[2 * e + 1] - mean) * rs * g1[cb + 2 * e + 1] + b1[cb + 2 * e + 1];
        pk[e] = (unsigned)f2bf(lo) | ((unsigned)f2bf(hi) << 16);
      }
      *(uint4*)(orow + j8 * 8) = make_uint4(pk[0], pk[1], pk[2], pk[3]);
    }
  }
}

// ---------------- MLP1: h1 = relu([x1t | msgN] @ W1^T), 128x128 tiles ----------------
__global__ __launch_bounds__(256) void mlp1_kernel(const u16* __restrict__ A1,
                                                   const u16* __restrict__ A2,
                                                   const u16* __restrict__ W,
                                                   u16* __restrict__ outp) {
  __shared__ u16 As[128][72];
  __shared__ u16 Ws[128][72];
  const int m0 = blockIdx.x * 128, o0 = blockIdx.y * 128;
  const int tid = threadIdx.x, lane = tid & 63, wave = tid >> 6;
  const int wm = (wave >> 1) * 64, wo = (wave & 1) * 64;
  const int fr = lane & 15, fq = lane >> 4;
  f32x4 acc[4][4] = {};
  for (int kt = 0; kt < 8; ++kt) {
    const int k0 = kt << 6;
    const u16* Ap = (k0 < 256) ? (A1 + k0) : (A2 + (k0 - 256));
#pragma unroll
    for (int i = 0; i < 4; ++i) {
      int idx = tid + i * 256;
      int r = idx >> 3, s = idx & 7;
      *(uint4*)(&As[r][s * 8]) = *(const uint4*)(Ap + (size_t)(m0 + r) * CC + s * 8);
      *(uint4*)(&Ws[r][s * 8]) = *(const uint4*)(W + (size_t)(o0 + r) * 512 + k0 + s * 8);
    }
    __syncthreads();
#pragma unroll
    for (int kk = 0; kk < 2; ++kk) {
      bf16x8 af[4], bfr[4];
#pragma unroll
      for (int mi = 0; mi < 4; ++mi)
        af[mi] = __builtin_bit_cast(bf16x8, *(const uint4*)(&As[wm + mi * 16 + fr][kk * 32 + fq * 8]));
#pragma unroll
      for (int oi = 0; oi < 4; ++oi)
        bfr[oi] = __builtin_bit_cast(bf16x8, *(const uint4*)(&Ws[wo + oi * 16 + fr][kk * 32 + fq * 8]));
#pragma unroll
      for (int mi = 0; mi < 4; ++mi)
#pragma unroll
        for (int oi = 0; oi < 4; ++oi)
          acc[mi][oi] = __builtin_amdgcn_mfma_f32_16x16x32_bf16(af[mi], bfr[oi], acc[mi][oi], 0, 0, 0);
    }
    __syncthreads();
  }
#pragma unroll
  for (int oi = 0; oi < 4; ++oi) {
    const int col = o0 + wo + oi * 16 + fr;
#pragma unroll
    for (int mi = 0; mi < 4; ++mi) {
      const int rowb = m0 + wm + mi * 16 + fq * 4;
#pragma unroll
      for (int r = 0; r < 4; ++r)
        outp[(size_t)(rowb + r) * 512 + col] = f2bf(fmaxf(acc[mi][oi][r], 0.f));
    }
  }
}

// ---------------- mlp2fused: MLP2 + LN2 + aug + transpose + x1-add -> out (f32) ----------------
// block: 128 rows x all 256 cols, K=512; 512 threads (8 waves, 2x4)
__global__ __launch_bounds__(512) void mlp2fused_kernel(const u16* __restrict__ h1,
                                                        const u16* __restrict__ W2b,
                                                        const u16* __restrict__ augt,
                                                        const float* __restrict__ x1,
                                                        const float* __restrict__ g2,
                                                        const float* __restrict__ b2,
                                                        float* __restrict__ outp) {
  // staging: As[128][72] + Ws[256][72] (27648 u16); phase B: Tl[128][272] (34816 u16)
  __shared__ u16 lds[128 * 272];
  u16* As = lds;
  u16* Ws = lds + 128 * 72;
  u16* Tl = lds;
  const int m0 = blockIdx.x * 128;  // global row
  const int b = m0 >> 13, nb = m0 & (NN - 1);
  const int tid = threadIdx.x, lane = tid & 63, w = tid >> 6;
  const int wm = (w >> 2) * 64, wo = (w & 3) * 64;
  const int fr = lane & 15, fq = lane >> 4;
  f32x4 acc[4][4] = {};
  for (int kt = 0; kt < 8; ++kt) {
    const int k0 = kt << 6;
#pragma unroll
    for (int i = 0; i < 2; ++i) {
      int idx = tid + i * 512;
      int rr = idx >> 3, ss = idx & 7;
      *(uint4*)(&As[rr * 72 + ss * 8]) = *(const uint4*)(h1 + (size_t)(m0 + rr) * 512 + k0 + ss * 8);
    }
#pragma unroll
    for (int i = 0; i < 4; ++i) {
      int idx = tid + i * 512;
      int rr = idx >> 3, ss = idx & 7;
      *(uint4*)(&Ws[rr * 72 + ss * 8]) = *(const uint4*)(W2b + (size_t)rr * 512 + k0 + ss * 8);
    }
    __syncthreads();
#pragma unroll
    for (int kk = 0; kk < 2; ++kk) {
      bf16x8 af[4], bfr[4];
#pragma unroll
      for (int mi = 0; mi < 4; ++mi)
        af[mi] = __builtin_bit_cast(bf16x8, *(const uint4*)(&As[(wm + mi * 16 + fr) * 72 + kk * 32 + fq * 8]));
#pragma unroll
      for (int oi = 0; oi < 4; ++oi)
        bfr[oi] = __builtin_bit_cast(bf16x8, *(const uint4*)(&Ws[(wo + oi * 16 + fr) * 72 + kk * 32 + fq * 8]));
#pragma unroll
      for (int mi = 0; mi < 4; ++mi)
#pragma unroll
        for (int oi = 0; oi < 4; ++oi)
          acc[mi][oi] = __builtin_amdgcn_mfma_f32_16x16x32_bf16(af[mi], bfr[oi], acc[mi][oi], 0, 0, 0);
    }
    __syncthreads();
  }
  // write raw mlp2 to Tl (bf16); As/Ws dead after final barrier above
#pragma unroll
  for (int oi = 0; oi < 4; ++oi) {
    const int col = wo + oi * 16 + fr;
#pragma unroll
    for (int mi = 0; mi < 4; ++mi) {
#pragma unroll
      for (int r = 0; r < 4; ++r) {
        const int row = wm + mi * 16 + fq * 4 + r;
        Tl[row * 272 + col] = f2bf(acc[mi][oi][r]);
      }
    }
  }
  __syncthreads();
  // LN2 + aug: 4 threads/row, write back to Tl in place (own quarter only)
  {
    const int row = tid >> 2, q = tid & 3;
    u16* mrow = &Tl[row * 272 + q * 64];
    float s1 = 0.f, s2 = 0.f;
#pragma unroll
    for (int j8 = 0; j8 < 8; ++j8) {
      uint4 raw = *(const uint4*)(mrow + j8 * 8);
      float f[8];
      bf8_to_f32(raw, f);
#pragma unroll
      for (int j = 0; j < 8; ++j) {
        s1 += f[j];
        s2 += f[j] * f[j];
      }
    }
    s1 += __shfl_xor(s1, 1); s2 += __shfl_xor(s2, 1);
    s1 += __shfl_xor(s1, 2); s2 += __shfl_xor(s2, 2);
    const float mean = s1 * (1.f / CC);
    const float var = s2 * (1.f / CC) - mean * mean;
    const float rs = rsqrtf(var + 1e-5f);
    const u16* arow = augt + ((size_t)b * NN + nb + row) * CC + q * 64;
#pragma unroll
    for (int j8 = 0; j8 < 8; ++j8) {
      uint4 raw = *(const uint4*)(mrow + j8 * 8);
      uint4 ar = *(const uint4*)(arow + j8 * 8);
      float f[8], af[8];
      bf8_to_f32(raw, f);
      bf8_to_f32(ar, af);
      const int cb = q * 64 + j8 * 8;
      unsigned pk[4];
#pragma unroll
      for (int e = 0; e < 4; ++e) {
        float lo = (f[2 * e] - mean) * rs * g2[cb + 2 * e] + b2[cb + 2 * e] + af[2 * e];
        float hi = (f[2 * e + 1] - mean) * rs * g2[cb + 2 * e + 1] + b2[cb + 2 * e + 1] + af[2 * e + 1];
        pk[e] = (unsigned)f2bf(lo) | ((unsigned)f2bf(hi) << 16);
      }
      *(uint4*)(mrow + j8 * 8) = make_uint4(pk[0], pk[1], pk[2], pk[3]);
    }
  }
  __syncthreads();
  // transposed output with x1 residual: out[b,c,nb+n] = Tl[n][c] + x1[b,c,nb+n]
#pragma unroll
  for (int i = 0; i < 64; ++i) {
    int idx = tid + i * 512;       // 0..32767
    int n = idx & 127, c = idx >> 7;
    size_t off = ((size_t)b * CC + c) * NN + nb + n;
    outp[off] = bf2f(Tl[n * 272 + c]) + x1[off];
  }
}

extern "C" void kernel_launch(void* const* d_in, const int* in_sizes, int n_in,
                              void* d_out, int out_size, void* d_ws, size_t ws_size,
                              hipStream_t stream) {
  (void)in_sizes; (void)n_in; (void)out_size; (void)ws_size;
  const float* x1 = (const float*)d_in[0];
  const float* x2 = (const float*)d_in[1];
  const float* Wq = (const float*)d_in[2];
  const float* bq = (const float*)d_in[3];
  const float* Wk = (const float*)d_in[4];
  const float* bk = (const float*)d_in[5];
  const float* Wv = (const float*)d_in[6];
  const float* bv = (const float*)d_in[7];
  const float* thr = (const float*)d_in[8];
  const float* W1 = (const float*)d_in[9];
  const float* W2 = (const float*)d_in[10];
  const float* g1 = (const float*)d_in[11];
  const float* b1 = (const float*)d_in[12];
  const float* g2 = (const float*)d_in[13];
  const float* b2 = (const float*)d_in[14];
  const float* Wa = (const float*)d_in[15];
  const float* ba = (const float*)d_in[16];
  const float* bng = (const float*)d_in[17];
  const float* bnb = (const float*)d_in[18];
  const float* bnm = (const float*)d_in[19];
  const float* bnv = (const float*)d_in[20];
  float* out = (float*)d_out;

  // Slot lifetime map (SZ = 16.78 MB each; strictly stream-ordered):
  //  slot 0: x1t                  (live entire call)
  //  slot 1: x2t                  (dead after proj_all)
  //  slot 2: Qt  -> h1(lo half)   (Qt consumed by bigmsg; h1 written by mlp1)
  //  slot 3: K2  -> h1(hi half)   (K2 consumed by kvpartial)
  //  slot 4: V2  -> msgN          (V2 dead after kvpartial; msgN: bigmsg w -> mlp1 r)
  //  slot 5: augt                 (live until mlp2fused)
  //  slot 6: Pkv (4 MB)           (kvpartial w -> kvreduce r)
  char* ws = (char*)d_ws;
  constexpr size_t SZ = (size_t)BB * NN * CC * sizeof(u16);  // 16.78 MB
  u16* x1t = (u16*)(ws);
  u16* x2t = (u16*)(ws + SZ);
  u16* Qt = (u16*)(ws + 2 * SZ);
  u16* K2 = (u16*)(ws + 3 * SZ);  // [B,C,N]
  u16* V2 = (u16*)(ws + 4 * SZ);  // [B,C,N]
  u16* augt = (u16*)(ws + 5 * SZ);
  float* Pkv = (float*)(ws + 6 * SZ);  // 4 MB
  u16* h1 = Qt;    // slots 2+3 contiguous (32768 x 512 bf16)
  u16* msgN = V2;  // slot 4 after V2 dead
  char* tail = ws + 7 * SZ;
  float* Ksum = (float*)tail;                      // 4 KB
  u16* KVT = (u16*)(tail + 4096);                  // 128 KB
  float* Pks = (float*)(tail + 4096 + 131072);     // 64 KB
  u16* Wqb = (u16*)(tail + 4096 + 131072 + 65536);
  u16* Wkb = Wqb + CC * CC;
  u16* Wvb = Wkb + CC * CC;
  u16* Wab = Wvb + CC * CC;
  u16* W1b = Wab + CC * CC;
  u16* W2b = W1b + 512 * 512;
  // total ws use ~119 MiB

  cvt_all_kernel<<<dim3(2560), 256, 0, stream>>>(Wq, Wk, Wv, Wa, W1, W2,
                                                 Wqb, Wkb, Wvb, Wab, W1b, W2b);
  transpose_kernel<<<dim3(NN / 64, CC / 64, 2 * BB), 256, 0, stream>>>(x1, x2, x1t, x2t);
  proj_all_kernel<<<dim3(256, 2, 4), 256, 0, stream>>>(
      x1t, x2t, Wqb, Wkb, Wvb, Wab, bq, bk, bv, ba, bng, bnb, bnm, bnv,
      Qt, K2, V2, augt);
  kvpartial_kernel<<<dim3(NCH, HH, BB), 256, 0, stream>>>(K2, V2, Pkv, Pks);
  kvreduce_kernel<<<dim3(256), 256, 0, stream>>>(Pkv, Pks, KVT, Ksum);
  bigmsg_kernel<<<dim3(NN / 64, 1, BB), 256, 0, stream>>>(Qt, KVT, Ksum, thr, g1, b1, msgN);
  mlp1_kernel<<<dim3(256, 4), 256, 0, stream>>>(x1t, msgN, W1b, h1);
  mlp2fused_kernel<<<dim3(256), 512, 0, stream>>>(h1, W2b, augt, x1, g2, b2, out);
}